// Round 10
// baseline (185.314 us; speedup 1.0000x reference)
//
#include <hip/hip_runtime.h>
#include <math.h>

#define NUM_ENT  50000
#define NUM_REL  64
#define NUM_TRI  400000
#define DIN      128
#define CAP      64                      // per-tail bucket capacity (deg~Poisson(8))

// K1 partitions
#define PACK_BLOCKS  24                  // 24*256*8 = 49152 = 3*128*128
#define SMALL_BLOCKS 64
#define ZERO_BLOCKS  196                 // ceil(50000/256)
#define PREP_BLOCKS  (PACK_BLOCKS + SMALL_BLOCKS + ZERO_BLOCKS)

// K2: [scat | gemm] INTERLEAVED block mapping (r9: 67->58us vs appended order).
//   b%3==0 -> scat task b/3 (391 tasks); else gemm tile (b/3)*2 + b%3 - 1 (782).
#define SCAT_BLOCKS  391                 // ceil(400000/1024): 4 triplets/thread
#define ENT_BLOCKS   782                 // ceil(50000/64)
#define MID_BLOCKS   (SCAT_BLOCKS + ENT_BLOCKS)      // 1173 = 3*391

typedef __attribute__((ext_vector_type(8))) short bf16x8;
typedef __attribute__((ext_vector_type(4))) float f32x4;

// fp32 -> bf16 bits, round-to-nearest-even
__device__ __forceinline__ unsigned short f2bf(float f) {
    unsigned u = __float_as_uint(f);
    unsigned r = ((u >> 16) & 1u) + 0x7fffu;
    return (unsigned short)((u + r) >> 16);
}

// --- packed-friendly bf16 loads (explicit dword unpack: d<<16 / d&0xffff0000) ---
__device__ __forceinline__ f32x4 ldbf4v(const unsigned short* p) {
    uint2 d = *(const uint2*)p;
    f32x4 v;
    v[0] = __uint_as_float(d.x << 16);
    v[1] = __uint_as_float(d.x & 0xffff0000u);
    v[2] = __uint_as_float(d.y << 16);
    v[3] = __uint_as_float(d.y & 0xffff0000u);
    return v;
}
__device__ __forceinline__ void ldbf8v(const unsigned short* p, f32x4* lo, f32x4* hi) {
    uint4 d = *(const uint4*)p;
    f32x4 a, b;
    a[0] = __uint_as_float(d.x << 16);
    a[1] = __uint_as_float(d.x & 0xffff0000u);
    a[2] = __uint_as_float(d.y << 16);
    a[3] = __uint_as_float(d.y & 0xffff0000u);
    b[0] = __uint_as_float(d.z << 16);
    b[1] = __uint_as_float(d.z & 0xffff0000u);
    b[2] = __uint_as_float(d.w << 16);
    b[3] = __uint_as_float(d.w & 0xffff0000u);
    *lo = a; *hi = b;
}

// attention dot with av folded in: sum_i tanh(x_i)*av_i
//   = sumAv + sum_i m2av_i * rcp(2^{x_i*2log2e} + 1),   m2av = -2*av.
// exp2 form folds the 2x into one packed constant mul. Saturation exact at +-inf.
// (exp-form validated rounds 7-9, absmax 0.015625; exp2 is the same function.)
__device__ __forceinline__ float att_p(f32x4 x, f32x4 m2av, float sumAv) {
    f32x4 xs = x * 2.885390081777927f;    // 2*log2(e)
    float r0 = __builtin_amdgcn_rcpf(exp2f(xs[0]) + 1.f);
    float r1 = __builtin_amdgcn_rcpf(exp2f(xs[1]) + 1.f);
    float r2 = __builtin_amdgcn_rcpf(exp2f(xs[2]) + 1.f);
    float r3 = __builtin_amdgcn_rcpf(exp2f(xs[3]) + 1.f);
    return fmaf(m2av[0], r0, fmaf(m2av[1], r1, fmaf(m2av[2], r2, fmaf(m2av[3], r3, sumAv))));
}

// ---------------- K1: [pack W frags | rel tables (f32, interleaved) | zero deg] ----------
// Bpack flat index: (((s*8 + t)*4 + ks)*64 + lane)*8 + j
//   holds W_s[k = ks*32 + (lane>>4)*8 + j][n = t*16 + (lane&15)] as bf16.
// TaTgF row r (256 floats): pos 8*(n>>2)+(n&3) = Ta[n], pos 8*(n>>2)+4+(n&3) = Tg[n].
// TaTgF stored f32 (64KB, L2-resident): removes 8 unpack ops/edge-lane in k_fused.
__global__ __launch_bounds__(256) void k_prep(const float* __restrict__ emb_rel,
                                              const float* __restrict__ Wa,
                                              const float* __restrict__ Wg,
                                              unsigned short* __restrict__ Bpack,
                                              float* __restrict__ TaTgF,
                                              int* __restrict__ deg) {
    __shared__ float s[DIN];
    int b = blockIdx.x;
    int tid = threadIdx.x;

    if (b < PACK_BLOCKS) {
        for (int i = 0; i < 8; i++) {
            int idx = b * 2048 + i * 256 + tid;       // < 49152
            int j    = idx & 7;
            int lane = (idx >> 3) & 63;
            int ks   = (idx >> 9) & 3;
            int t    = (idx >> 11) & 7;
            int w    = idx >> 14;
            int k = ks * 32 + ((lane >> 4) << 3) + j;
            int n = t * 16 + (lane & 15);
            const float* W = (w == 0) ? Wa : (w == 1) ? (Wa + 128 * DIN) : Wg;
            Bpack[idx] = f2bf(W[k * DIN + n]);
        }
    } else if (b < PACK_BLOCKS + SMALL_BLOCKS) {
        int row = b - PACK_BLOCKS;
        if (tid < DIN) s[tid] = emb_rel[row * DIN + tid];
        __syncthreads();
        int j = tid & 127;
        const float* W = (tid < 128) ? (Wa + 256 * DIN) : (Wg + 128 * DIN);
        float acc = 0.f;
#pragma unroll 8
        for (int k = 0; k < DIN; k++) acc += s[k] * W[k * DIN + j];
        int pos = row * 256 + 8 * (j >> 2) + (j & 3) + ((tid < 128) ? 0 : 4);
        TaTgF[pos] = acc;
    } else {
        int idx = (b - PACK_BLOCKS - SMALL_BLOCKS) * 256 + tid;
        if (idx < NUM_ENT) deg[idx] = 0;
    }
}

// ---------------- K2: [bucket scatter || MFMA entity GEMMs] interleaved ----------
// gemm: operand-swapped MFMA, writes Pt (plain) and PhGh (interleaved rows of 256).
// scat: 4 triplets/thread via 3x int4, edge packed (h<<6)|r, compact 4B deg counters
// (r8 falsified line-striding: 64B-strided counters were SLOWER, 66-69 vs 60-63).
__global__ __launch_bounds__(256) void k_mid(const float* __restrict__ X,
                                             const unsigned short* __restrict__ Bpack,
                                             const int* __restrict__ trip,
                                             const float* __restrict__ ba,
                                             const float* __restrict__ bg,
                                             unsigned short* __restrict__ Pt,
                                             unsigned short* __restrict__ PhGh,
                                             int* __restrict__ deg,
                                             int* __restrict__ elist) {
    __shared__ unsigned short As[64][136];
    int b = blockIdx.x;
    int tid = threadIdx.x;
    int third = b / 3;
    int rem = b - third * 3;

    if (rem == 0) {
        // ---- scatter task 'third' in [0, 391) ----
        int i0 = third * 1024 + tid * 4;              // 4 consecutive triplets
        if (i0 < NUM_TRI) {                           // NUM_TRI % 4 == 0
            const int4* tp = (const int4*)&trip[i0 * 3];   // 48B, 16B-aligned
            int4 A = tp[0], B4 = tp[1], C4 = tp[2];
            int hs[4] = {A.x, A.w, B4.z, C4.y};
            int rs[4] = {A.y, B4.x, B4.w, C4.z};
            int ts[4] = {A.z, B4.y, C4.x, C4.w};
#pragma unroll
            for (int u = 0; u < 4; u++) {
                int pos = atomicAdd(&deg[ts[u]], 1);
                if (pos < CAP) elist[ts[u] * CAP + pos] = (hs[u] << 6) | rs[u];
            }
        }
    } else {
        // ---- gemm tile in [0, 782) ----
        int tile = third * 2 + rem - 1;
        int m0 = tile * 64;
        // coalesced stage of X tile as bf16
        for (int i = 0; i < 8; i++) {
            int v = tid + i * 256;
            int row = v >> 5;
            int c4 = v & 31;
            int gr = m0 + row;
            if (gr >= NUM_ENT) gr = NUM_ENT - 1;
            float4 x = *(const float4*)&X[gr * DIN + c4 * 4];
            ushort4 h;
            h.x = f2bf(x.x); h.y = f2bf(x.y); h.z = f2bf(x.z); h.w = f2bf(x.w);
            *(ushort4*)&As[row][c4 * 4] = h;
        }
        __syncthreads();

        int w = tid >> 6;
        int q = tid & 63;
        int quad = q >> 4;
        int lrow = w * 16 + (q & 15);
        int gr = m0 + lrow;

        bf16x8 a[4];
#pragma unroll
        for (int ks = 0; ks < 4; ks++)
            a[ks] = *(const bf16x8*)&As[lrow][ks * 32 + quad * 8];

        const bf16x8* Bp = (const bf16x8*)Bpack;
#pragma unroll
        for (int s = 0; s < 3; s++) {
            f32x4 acc[8];
#pragma unroll
            for (int t = 0; t < 8; t++) acc[t] = (f32x4){0.f, 0.f, 0.f, 0.f};
#pragma unroll
            for (int ks = 0; ks < 4; ks++) {
#pragma unroll
                for (int t = 0; t < 8; t++) {
                    bf16x8 wf = Bp[((s * 8 + t) * 4 + ks) * 64 + q];
                    acc[t] = __builtin_amdgcn_mfma_f32_16x16x32_bf16(wf, a[ks], acc[t], 0, 0, 0);
                }
            }
            if (gr < NUM_ENT) {
#pragma unroll
                for (int t = 0; t < 8; t++) {
                    int n0 = t * 16 + quad * 4;        // n0 % 4 == 0
                    float4 bb = make_float4(0.f, 0.f, 0.f, 0.f);
                    if (s == 0) bb = *(const float4*)&ba[n0];
                    if (s == 2) bb = *(const float4*)&bg[n0];
                    ushort4 o;
                    o.x = f2bf(acc[t][0] + bb.x);
                    o.y = f2bf(acc[t][1] + bb.y);
                    o.z = f2bf(acc[t][2] + bb.z);
                    o.w = f2bf(acc[t][3] + bb.w);
                    if (s == 0) {
                        *(ushort4*)&Pt[gr * DIN + n0] = o;
                    } else {
                        // interleaved: Ph at 2*n0, Gh at 2*n0+4 within row gr*256
                        *(ushort4*)&PhGh[gr * 256 + 2 * n0 + ((s == 1) ? 0 : 4)] = o;
                    }
                }
            }
        }
    }
}

// ---------------- K3: fused per-tail pass, one 64-lane wave per tail ----------
// Hot loop on ext-vector f32x4 ops -> v_pk_add_f32 / v_pk_fma_f32 (full-rate
// packed f32 on CDNA): ~halves the non-transcendental issue count.
// lanes 0-31 take even edges, 32-63 odd edges; merge is linear (exp-safe: |p|<=2).
// SHFL-DIVERGENCE RULE: divergent-trip loop iterations are half0-only (reads its
// own lanes: OK); the remainder can be half1-only, so its shfl MUST stay hoisted
// to the reconverged point before the `if` (exec-masked-lane read is undefined --
// produced absmax 2.39 when violated).
__global__ __launch_bounds__(256) void k_fused(const int* __restrict__ elist,
                                               const int* __restrict__ deg_arr,
                                               const unsigned short* __restrict__ Pt,
                                               const unsigned short* __restrict__ PhGh,
                                               const float* __restrict__ TaTgF,
                                               const float* __restrict__ attn_vec,
                                               float* __restrict__ out) {
    int tid = threadIdx.x;
    int wv = tid >> 6;
    int lane = tid & 63;
    int half = lane >> 5;
    int q = lane & 31;
    int t = blockIdx.x * 4 + wv;
    int deg = deg_arr[t];
    if (deg > CAP) deg = CAP;
    int c = q * 4;

    f32x4 pt4 = ldbf4v(&Pt[t * DIN + c]);
    f32x4 av4 = *(const f32x4*)&attn_vec[c];
    float sumAv = av4[0] + av4[1] + av4[2] + av4[3];
    f32x4 m2av = av4 * -2.f;

    // whole bucket in one coalesced load; slots >= deg never selected
    int eall = elist[t * CAP + lane];

    float l = 0.f;
    f32x4 acc = (f32x4){0.f, 0.f, 0.f, 0.f};
    f32x4 sTa = (f32x4){0.f, 0.f, 0.f, 0.f};
    f32x4 sTg = (f32x4){0.f, 0.f, 0.f, 0.f};

    int it = half;
    for (; it + 2 < deg; it += 4) {
        int e0 = __shfl(eall, it);
        int e1 = __shfl(eall, it + 2);
        int h0 = e0 >> 6, r0 = e0 & 63;
        int h1 = e1 >> 6, r1 = e1 & 63;
        const float* t0p = &TaTgF[r0 * 256 + q * 8];
        const float* t1p = &TaTgF[r1 * 256 + q * 8];
        f32x4 ta0 = *(const f32x4*)t0p;
        f32x4 tg0 = *(const f32x4*)(t0p + 4);
        f32x4 ph0, gh0;
        ldbf8v(&PhGh[h0 * 256 + q * 8], &ph0, &gh0);
        f32x4 ta1 = *(const f32x4*)t1p;
        f32x4 tg1 = *(const f32x4*)(t1p + 4);
        f32x4 ph1, gh1;
        ldbf8v(&PhGh[h1 * 256 + q * 8], &ph1, &gh1);

        sTa += ta0 + ta1;
        sTg += tg0 + tg1;
        f32x4 x0 = pt4 + ph0 + ta0;
        f32x4 x1 = pt4 + ph1 + ta1;
        f32x4 gm0 = gh0 + tg0;
        f32x4 gm1 = gh1 + tg1;
        float p0 = att_p(x0, m2av, sumAv);
        float p1 = att_p(x1, m2av, sumAv);
        p0 += __shfl_xor(p0, 1);
        p0 += __shfl_xor(p0, 2);
        p1 += __shfl_xor(p1, 1);
        p1 += __shfl_xor(p1, 2);
        float w0 = __expf(p0);
        float w1 = __expf(p1);
        l += w0 + w1;
        acc += gm0 * w0;
        acc += gm1 * w1;
    }
    // remainder: shfl hoisted to reconverged control flow (all 64 lanes execute);
    // lanes with it >= deg read a dummy legal index and discard the value.
    {
        int e = __shfl(eall, it & (CAP - 1));
        if (it < deg) {
            int h = e >> 6;
            int r = e & 63;
            const float* tp = &TaTgF[r * 256 + q * 8];
            f32x4 ta = *(const f32x4*)tp;
            f32x4 tg = *(const f32x4*)(tp + 4);
            f32x4 ph, gh;
            ldbf8v(&PhGh[h * 256 + q * 8], &ph, &gh);
            sTa += ta;
            sTg += tg;
            f32x4 x = pt4 + ph + ta;
            f32x4 gm = gh + tg;
            float p = att_p(x, m2av, sumAv);
            p += __shfl_xor(p, 1);
            p += __shfl_xor(p, 2);
            float w = __expf(p);
            l += w;
            acc += gm * w;
        }
    }

    // merge the two halves (linear: no running max needed)
    l      += __shfl_xor(l, 32);
    acc[0] += __shfl_xor(acc[0], 32);
    acc[1] += __shfl_xor(acc[1], 32);
    acc[2] += __shfl_xor(acc[2], 32);
    acc[3] += __shfl_xor(acc[3], 32);
    sTa[0] += __shfl_xor(sTa[0], 32);
    sTa[1] += __shfl_xor(sTa[1], 32);
    sTa[2] += __shfl_xor(sTa[2], 32);
    sTa[3] += __shfl_xor(sTa[3], 32);
    sTg[0] += __shfl_xor(sTg[0], 32);
    sTg[1] += __shfl_xor(sTg[1], 32);
    sTg[2] += __shfl_xor(sTg[2], 32);
    sTg[3] += __shfl_xor(sTg[3], 32);

    // self edge: both halves compute identical values (merged inputs)
    {
        float inv = (deg > 0) ? __builtin_amdgcn_rcpf((float)deg) : 0.f;
        f32x4 pa, gm;
        ldbf8v(&PhGh[t * 256 + q * 8], &pa, &gm);
        pa += sTa * inv;
        gm += sTg * inv;
        f32x4 x = pt4 + pa;
        float p = att_p(x, m2av, sumAv);
        p += __shfl_xor(p, 1);
        p += __shfl_xor(p, 2);
        float w = __expf(p);
        l += w;
        acc += gm * w;
    }
    float invl = 1.f / (l + 1e-16f);
    if (half == 0) {
        *(f32x4*)&out[t * DIN + c] = acc * invl;
    }
}

extern "C" void kernel_launch(void* const* d_in, const int* in_sizes, int n_in,
                              void* d_out, int out_size, void* d_ws, size_t ws_size,
                              hipStream_t stream) {
    const float* emb_ent  = (const float*)d_in[0];
    const float* emb_rel  = (const float*)d_in[1];
    const int*   trip     = (const int*)d_in[2];
    const float* Wa       = (const float*)d_in[3];
    const float* ba       = (const float*)d_in[4];
    const float* attn_vec = (const float*)d_in[5];
    const float* Wg       = (const float*)d_in[6];
    const float* bg       = (const float*)d_in[7];
    float* out = (float*)d_out;

    // workspace layout: bf16 region, then f32 table, then int region
    unsigned short* wsh = (unsigned short*)d_ws;
    unsigned short* Pt    = wsh;                      //  6,400,000 us
    unsigned short* PhGh  = wsh + 6400000;            // 12,800,000 us (interleaved)
    unsigned short* Bpack = wsh + 19200000;           //     49,152 us
    float* TaTgF = (float*)(wsh + 19249152);          //     16,384 floats (64KB)
    int*   deg   = (int*)(TaTgF + 16384);             //     50,000 (zeroed in K1)
    int*   elist = deg + 50000;                       // 50,000*64 int = 12.8 MB
    // total ~ 51.7 MB

    k_prep<<<PREP_BLOCKS, 256, 0, stream>>>(emb_rel, Wa, Wg, Bpack, TaTgF, deg);

    k_mid<<<MID_BLOCKS, 256, 0, stream>>>(emb_ent, Bpack, trip, ba, bg,
                                          Pt, PhGh, deg, elist);

    k_fused<<<NUM_ENT / 4, 256, 0, stream>>>(elist, deg,
                                             Pt, PhGh, TaTgF, attn_vec, out);
}

// Round 11
// 174.339 us; speedup vs baseline: 1.0630x; 1.0630x over previous
//
#include <hip/hip_runtime.h>
#include <math.h>

#define NUM_ENT  50000
#define NUM_REL  64
#define NUM_TRI  400000
#define DIN      128
#define CAP      64                      // per-tail bucket capacity (deg~Poisson(8))

// K1 partitions
#define PACK_BLOCKS  24                  // 24*256*8 = 49152 = 3*128*128
#define SMALL_BLOCKS 64
#define ZERO_BLOCKS  196                 // ceil(50000/256)
#define PREP_BLOCKS  (PACK_BLOCKS + SMALL_BLOCKS + ZERO_BLOCKS)

// K2: [scat | gemm] 1:1 FRONT-INTERLEAVED mapping.
//   b<782: even b -> scat b/2 (391), odd b -> gemm b/2 (391);
//   b>=782: gemm 391 + (b-782) (remaining 391).
// r9 measured 1-in-3 interleave: mid=58us > max(scat~48, gemm~18) -- scatter
// waves were only ~33% of residency, under-saturating the atomic unit. 1:1
// front-loading doubles scatter's resident share while it lives.
#define SCAT_BLOCKS  391                 // ceil(400000/1024): 4 triplets/thread
#define ENT_BLOCKS   782                 // ceil(50000/64)
#define MID_BLOCKS   (SCAT_BLOCKS + ENT_BLOCKS)      // 1173

typedef __attribute__((ext_vector_type(8))) short bf16x8;
typedef __attribute__((ext_vector_type(8))) unsigned short u16x8;
typedef __attribute__((ext_vector_type(4))) float f32x4;

__device__ __forceinline__ float4 f4add(float4 a, float4 b) {
    return make_float4(a.x + b.x, a.y + b.y, a.z + b.z, a.w + b.w);
}

// fp32 -> bf16 bits, round-to-nearest-even
__device__ __forceinline__ unsigned short f2bf(float f) {
    unsigned u = __float_as_uint(f);
    unsigned r = ((u >> 16) & 1u) + 0x7fffu;
    return (unsigned short)((u + r) >> 16);
}
__device__ __forceinline__ float bf2f(unsigned short h) {
    return __uint_as_float(((unsigned)h) << 16);
}
__device__ __forceinline__ float4 ldbf4(const unsigned short* p) {
    ushort4 u = *(const ushort4*)p;
    return make_float4(bf2f(u.x), bf2f(u.y), bf2f(u.z), bf2f(u.w));
}
// load 8 interleaved bf16 with ONE 16B load -> two float4 (first 4, last 4)
__device__ __forceinline__ void ldbf8(const unsigned short* p, float4* lo, float4* hi) {
    u16x8 u = *(const u16x8*)p;
    *lo = make_float4(bf2f(u[0]), bf2f(u[1]), bf2f(u[2]), bf2f(u[3]));
    *hi = make_float4(bf2f(u[4]), bf2f(u[5]), bf2f(u[6]), bf2f(u[7]));
}

// attention dot with av folded in: sum_i tanh(x_i)*av_i
//   = sumAv + sum_i m2av_i * rcp(e^{2 x_i} + 1),   m2av = -2*av.
// Saturates correctly at +-inf. Validated rounds 7-9 (absmax 0.015625).
// (r10 lesson: packed-f32/exp2/f32-table rewrite did NOT cut VALU cycles and
//  added gather latency -- k_fused 48->64us. This exp-form bf16 version is
//  the measured-best; do not "optimize" it without a verified cycle cut.)
__device__ __forceinline__ float att_p(float4 x, float4 m2av, float sumAv) {
    float r0 = __builtin_amdgcn_rcpf(__expf(2.f * x.x) + 1.f);
    float r1 = __builtin_amdgcn_rcpf(__expf(2.f * x.y) + 1.f);
    float r2 = __builtin_amdgcn_rcpf(__expf(2.f * x.z) + 1.f);
    float r3 = __builtin_amdgcn_rcpf(__expf(2.f * x.w) + 1.f);
    return fmaf(m2av.x, r0, fmaf(m2av.y, r1, fmaf(m2av.z, r2, fmaf(m2av.w, r3, sumAv))));
}

// ---------------- K1: [pack W frags | rel tables (interleaved) | zero deg] ----------
// Bpack flat index: (((s*8 + t)*4 + ks)*64 + lane)*8 + j
//   holds W_s[k = ks*32 + (lane>>4)*8 + j][n = t*16 + (lane&15)] as bf16.
// TaTg row r (256 us): pos 8*(n>>2)+(n&3) = Ta[n], pos 8*(n>>2)+4+(n&3) = Tg[n].
__global__ __launch_bounds__(256) void k_prep(const float* __restrict__ emb_rel,
                                              const float* __restrict__ Wa,
                                              const float* __restrict__ Wg,
                                              unsigned short* __restrict__ Bpack,
                                              unsigned short* __restrict__ TaTg,
                                              int* __restrict__ deg) {
    __shared__ float s[DIN];
    int b = blockIdx.x;
    int tid = threadIdx.x;

    if (b < PACK_BLOCKS) {
        for (int i = 0; i < 8; i++) {
            int idx = b * 2048 + i * 256 + tid;       // < 49152
            int j    = idx & 7;
            int lane = (idx >> 3) & 63;
            int ks   = (idx >> 9) & 3;
            int t    = (idx >> 11) & 7;
            int w    = idx >> 14;
            int k = ks * 32 + ((lane >> 4) << 3) + j;
            int n = t * 16 + (lane & 15);
            const float* W = (w == 0) ? Wa : (w == 1) ? (Wa + 128 * DIN) : Wg;
            Bpack[idx] = f2bf(W[k * DIN + n]);
        }
    } else if (b < PACK_BLOCKS + SMALL_BLOCKS) {
        int row = b - PACK_BLOCKS;
        if (tid < DIN) s[tid] = emb_rel[row * DIN + tid];
        __syncthreads();
        int j = tid & 127;
        const float* W = (tid < 128) ? (Wa + 256 * DIN) : (Wg + 128 * DIN);
        float acc = 0.f;
#pragma unroll 8
        for (int k = 0; k < DIN; k++) acc += s[k] * W[k * DIN + j];
        int pos = row * 256 + 8 * (j >> 2) + (j & 3) + ((tid < 128) ? 0 : 4);
        TaTg[pos] = f2bf(acc);
    } else {
        int idx = (b - PACK_BLOCKS - SMALL_BLOCKS) * 256 + tid;
        if (idx < NUM_ENT) deg[idx] = 0;
    }
}

// ---------------- K2: [bucket scatter || MFMA entity GEMMs] 1:1 front-interleaved ----------
// gemm: operand-swapped MFMA, writes Pt (plain) and PhGh (interleaved rows of 256).
// scat: 4 triplets/thread via 3x int4, edge packed (h<<6)|r, compact 4B deg counters
// (r8 falsified line-striding: 64B-strided counters were SLOWER, 66-69 vs 60-63).
__global__ __launch_bounds__(256) void k_mid(const float* __restrict__ X,
                                             const unsigned short* __restrict__ Bpack,
                                             const int* __restrict__ trip,
                                             const float* __restrict__ ba,
                                             const float* __restrict__ bg,
                                             unsigned short* __restrict__ Pt,
                                             unsigned short* __restrict__ PhGh,
                                             int* __restrict__ deg,
                                             int* __restrict__ elist) {
    __shared__ unsigned short As[64][136];
    int b = blockIdx.x;
    int tid = threadIdx.x;

    int sc = -1, tile;
    if (b < 2 * SCAT_BLOCKS) {
        if ((b & 1) == 0) sc = b >> 1;                // scat tasks 0..390
        else tile = b >> 1;                           // gemm tiles 0..390
    } else {
        tile = b - SCAT_BLOCKS;                       // gemm tiles 391..781
    }

    if (sc >= 0) {
        // ---- scatter task ----
        int i0 = sc * 1024 + tid * 4;                 // 4 consecutive triplets
        if (i0 < NUM_TRI) {                           // NUM_TRI % 4 == 0
            const int4* tp = (const int4*)&trip[i0 * 3];   // 48B, 16B-aligned
            int4 A = tp[0], B4 = tp[1], C4 = tp[2];
            int hs[4] = {A.x, A.w, B4.z, C4.y};
            int rs[4] = {A.y, B4.x, B4.w, C4.z};
            int ts[4] = {A.z, B4.y, C4.x, C4.w};
#pragma unroll
            for (int u = 0; u < 4; u++) {
                int pos = atomicAdd(&deg[ts[u]], 1);
                if (pos < CAP) elist[ts[u] * CAP + pos] = (hs[u] << 6) | rs[u];
            }
        }
    } else {
        // ---- gemm tile in [0, 782) ----
        int m0 = tile * 64;
        // coalesced stage of X tile as bf16
        for (int i = 0; i < 8; i++) {
            int v = tid + i * 256;
            int row = v >> 5;
            int c4 = v & 31;
            int gr = m0 + row;
            if (gr >= NUM_ENT) gr = NUM_ENT - 1;
            float4 x = *(const float4*)&X[gr * DIN + c4 * 4];
            ushort4 h;
            h.x = f2bf(x.x); h.y = f2bf(x.y); h.z = f2bf(x.z); h.w = f2bf(x.w);
            *(ushort4*)&As[row][c4 * 4] = h;
        }
        __syncthreads();

        int w = tid >> 6;
        int q = tid & 63;
        int quad = q >> 4;
        int lrow = w * 16 + (q & 15);
        int gr = m0 + lrow;

        bf16x8 a[4];
#pragma unroll
        for (int ks = 0; ks < 4; ks++)
            a[ks] = *(const bf16x8*)&As[lrow][ks * 32 + quad * 8];

        const bf16x8* Bp = (const bf16x8*)Bpack;
#pragma unroll
        for (int s = 0; s < 3; s++) {
            f32x4 acc[8];
#pragma unroll
            for (int t = 0; t < 8; t++) acc[t] = (f32x4){0.f, 0.f, 0.f, 0.f};
#pragma unroll
            for (int ks = 0; ks < 4; ks++) {
#pragma unroll
                for (int t = 0; t < 8; t++) {
                    bf16x8 wf = Bp[((s * 8 + t) * 4 + ks) * 64 + q];
                    acc[t] = __builtin_amdgcn_mfma_f32_16x16x32_bf16(wf, a[ks], acc[t], 0, 0, 0);
                }
            }
            if (gr < NUM_ENT) {
#pragma unroll
                for (int t = 0; t < 8; t++) {
                    int n0 = t * 16 + quad * 4;        // n0 % 4 == 0
                    float4 bb = make_float4(0.f, 0.f, 0.f, 0.f);
                    if (s == 0) bb = *(const float4*)&ba[n0];
                    if (s == 2) bb = *(const float4*)&bg[n0];
                    ushort4 o;
                    o.x = f2bf(acc[t][0] + bb.x);
                    o.y = f2bf(acc[t][1] + bb.y);
                    o.z = f2bf(acc[t][2] + bb.z);
                    o.w = f2bf(acc[t][3] + bb.w);
                    if (s == 0) {
                        *(ushort4*)&Pt[gr * DIN + n0] = o;
                    } else {
                        // interleaved: Ph at 2*n0, Gh at 2*n0+4 within row gr*256
                        *(ushort4*)&PhGh[gr * 256 + 2 * n0 + ((s == 1) ? 0 : 4)] = o;
                    }
                }
            }
        }
    }
}

// ---------------- K3: fused per-tail pass, one 64-lane wave per tail ----------
// lanes 0-31 take even edges, 32-63 odd edges; merge is linear (exp-safe: |p|<=2).
// whole bucket's edge list loaded once (coalesced 256B) and distributed via shfl.
// per-half loop manually unrolled x2: both edges' gathers issued back-to-back (MLP=4).
// SHFL-DIVERGENCE RULE: divergent-trip loop iterations are half0-only (reads its
// own lanes: OK); the remainder can be half1-only, so its shfl MUST stay hoisted
// to the reconverged point before the `if` (exec-masked-lane read is undefined --
// produced absmax 2.39 when violated).
__global__ __launch_bounds__(256) void k_fused(const int* __restrict__ elist,
                                               const int* __restrict__ deg_arr,
                                               const unsigned short* __restrict__ Pt,
                                               const unsigned short* __restrict__ PhGh,
                                               const unsigned short* __restrict__ TaTg,
                                               const float* __restrict__ attn_vec,
                                               float* __restrict__ out) {
    int tid = threadIdx.x;
    int wv = tid >> 6;
    int lane = tid & 63;
    int half = lane >> 5;
    int q = lane & 31;
    int t = blockIdx.x * 4 + wv;
    int deg = deg_arr[t];
    if (deg > CAP) deg = CAP;
    int c = q * 4;

    float4 pt4 = ldbf4(&Pt[t * DIN + c]);
    float4 av4 = *(const float4*)&attn_vec[c];
    float sumAv = av4.x + av4.y + av4.z + av4.w;
    float4 m2av = make_float4(-2.f * av4.x, -2.f * av4.y, -2.f * av4.z, -2.f * av4.w);

    // whole bucket in one coalesced load; slots >= deg never selected
    int eall = elist[t * CAP + lane];

    float l = 0.f;
    float4 acc = make_float4(0.f, 0.f, 0.f, 0.f);
    float4 sTa = make_float4(0.f, 0.f, 0.f, 0.f);
    float4 sTg = make_float4(0.f, 0.f, 0.f, 0.f);

    int it = half;
    for (; it + 2 < deg; it += 4) {
        int e0 = __shfl(eall, it);
        int e1 = __shfl(eall, it + 2);
        int h0 = e0 >> 6, r0 = e0 & 63;
        int h1 = e1 >> 6, r1 = e1 & 63;
        float4 ta0, tg0, ph0, gh0, ta1, tg1, ph1, gh1;
        ldbf8(&TaTg[r0 * 256 + q * 8], &ta0, &tg0);
        ldbf8(&PhGh[h0 * 256 + q * 8], &ph0, &gh0);
        ldbf8(&TaTg[r1 * 256 + q * 8], &ta1, &tg1);
        ldbf8(&PhGh[h1 * 256 + q * 8], &ph1, &gh1);

        sTa = f4add(sTa, f4add(ta0, ta1));
        sTg = f4add(sTg, f4add(tg0, tg1));
        float4 pa0 = f4add(ph0, ta0);
        float4 gm0 = f4add(gh0, tg0);
        float4 pa1 = f4add(ph1, ta1);
        float4 gm1 = f4add(gh1, tg1);
        float p0 = att_p(f4add(pt4, pa0), m2av, sumAv);
        float p1 = att_p(f4add(pt4, pa1), m2av, sumAv);
        p0 += __shfl_xor(p0, 1);
        p0 += __shfl_xor(p0, 2);
        p1 += __shfl_xor(p1, 1);
        p1 += __shfl_xor(p1, 2);
        float w0 = __expf(p0);
        float w1 = __expf(p1);
        l += w0 + w1;
        acc.x += w0 * gm0.x + w1 * gm1.x;
        acc.y += w0 * gm0.y + w1 * gm1.y;
        acc.z += w0 * gm0.z + w1 * gm1.z;
        acc.w += w0 * gm0.w + w1 * gm1.w;
    }
    // remainder: shfl hoisted to reconverged control flow (all 64 lanes execute);
    // lanes with it >= deg read a dummy legal index and discard the value.
    {
        int e = __shfl(eall, it & (CAP - 1));
        if (it < deg) {
            int h = e >> 6;
            int r = e & 63;
            float4 ta, tg, ph, gh;
            ldbf8(&TaTg[r * 256 + q * 8], &ta, &tg);
            ldbf8(&PhGh[h * 256 + q * 8], &ph, &gh);
            sTa = f4add(sTa, ta);
            sTg = f4add(sTg, tg);
            float4 pa = f4add(ph, ta);
            float4 gm = f4add(gh, tg);
            float p = att_p(f4add(pt4, pa), m2av, sumAv);
            p += __shfl_xor(p, 1);
            p += __shfl_xor(p, 2);
            float w = __expf(p);
            l += w;
            acc.x += w * gm.x; acc.y += w * gm.y; acc.z += w * gm.z; acc.w += w * gm.w;
        }
    }

    // merge the two halves (linear: no running max needed)
    l     += __shfl_xor(l, 32);
    acc.x += __shfl_xor(acc.x, 32);
    acc.y += __shfl_xor(acc.y, 32);
    acc.z += __shfl_xor(acc.z, 32);
    acc.w += __shfl_xor(acc.w, 32);
    sTa.x += __shfl_xor(sTa.x, 32);
    sTa.y += __shfl_xor(sTa.y, 32);
    sTa.z += __shfl_xor(sTa.z, 32);
    sTa.w += __shfl_xor(sTa.w, 32);
    sTg.x += __shfl_xor(sTg.x, 32);
    sTg.y += __shfl_xor(sTg.y, 32);
    sTg.z += __shfl_xor(sTg.z, 32);
    sTg.w += __shfl_xor(sTg.w, 32);

    // self edge: both halves compute identical values (merged inputs)
    {
        float inv = (deg > 0) ? __builtin_amdgcn_rcpf((float)deg) : 0.f;
        float4 pa, gm;
        ldbf8(&PhGh[t * 256 + q * 8], &pa, &gm);
        pa.x += sTa.x * inv; pa.y += sTa.y * inv; pa.z += sTa.z * inv; pa.w += sTa.w * inv;
        gm.x += sTg.x * inv; gm.y += sTg.y * inv; gm.z += sTg.z * inv; gm.w += sTg.w * inv;
        float p = att_p(f4add(pt4, pa), m2av, sumAv);
        p += __shfl_xor(p, 1);
        p += __shfl_xor(p, 2);
        float w = __expf(p);
        l += w;
        acc.x += w * gm.x; acc.y += w * gm.y; acc.z += w * gm.z; acc.w += w * gm.w;
    }
    float invl = 1.f / (l + 1e-16f);
    if (half == 0) {
        *(float4*)&out[t * DIN + c] =
            make_float4(acc.x * invl, acc.y * invl, acc.z * invl, acc.w * invl);
    }
}

extern "C" void kernel_launch(void* const* d_in, const int* in_sizes, int n_in,
                              void* d_out, int out_size, void* d_ws, size_t ws_size,
                              hipStream_t stream) {
    const float* emb_ent  = (const float*)d_in[0];
    const float* emb_rel  = (const float*)d_in[1];
    const int*   trip     = (const int*)d_in[2];
    const float* Wa       = (const float*)d_in[3];
    const float* ba       = (const float*)d_in[4];
    const float* attn_vec = (const float*)d_in[5];
    const float* Wg       = (const float*)d_in[6];
    const float* bg       = (const float*)d_in[7];
    float* out = (float*)d_out;

    // workspace layout: bf16 region then int region
    unsigned short* wsh = (unsigned short*)d_ws;
    unsigned short* Pt    = wsh;                      //  6,400,000 us
    unsigned short* PhGh  = wsh + 6400000;            // 12,800,000 us (interleaved)
    unsigned short* TaTg  = wsh + 19200000;           //     16,384 us (interleaved)
    unsigned short* Bpack = wsh + 19216384;           //     49,152
    int* deg   = (int*)(wsh + 19265536);              //     50,000 (zeroed in K1)
    int* elist = deg + 50000;                         // 50,000*64 int = 12.8 MB
    // total ~ 51.6 MB

    k_prep<<<PREP_BLOCKS, 256, 0, stream>>>(emb_rel, Wa, Wg, Bpack, TaTg, deg);

    k_mid<<<MID_BLOCKS, 256, 0, stream>>>(emb_ent, Bpack, trip, ba, bg,
                                          Pt, PhGh, deg, elist);

    k_fused<<<NUM_ENT / 4, 256, 0, stream>>>(elist, deg,
                                             Pt, PhGh, TaTg, attn_vec, out);
}